// Round 15
// baseline (126.545 us; speedup 1.0000x reference)
//
#include <hip/hip_runtime.h>
#include <math.h>

#define NB 4
#define NPT 4096
#define KNN 20
#define C1 64
#define C2 128
#define C3 256
#define BN_EPS 1e-5f

// pd = 2*dot(q,c) - |q|^2 - |c|^2 (== reference -xx - inner - cc), 4-instr form.
// q2 = {2qx, 2qy, 2qz, -|q|^2}. Same chain in both passes: selection self-consistent.
__device__ __forceinline__ float pd2_of(float4 q2, float4 c) {
#pragma clang fp contract(off)
  return fmaf(q2.x, c.x, fmaf(q2.y, c.y, fmaf(q2.z, c.z, q2.w - c.w)));
}

__device__ __forceinline__ unsigned long long rl_u64(unsigned long long v, int src) {
  unsigned lo = __builtin_amdgcn_readlane((unsigned)v, src);
  unsigned hi = __builtin_amdgcn_readlane((unsigned)(v >> 32), src);
  return ((unsigned long long)hi << 32) | lo;
}

// ---------------- K1: fused pack + exact kNN + edge-conv(6->64)+BN+ReLU+maxK ----------------
// R9 structure (loop pragmas untouched -- R10 showed full unroll => spill), pd now 4 instr.
// 512-thr blocks (8 waves), wave owns 4 queries (one ds_read_b128 feeds 4 pd).
// Pass1: lane-max + bitonic -> m = 20th-largest lane-max (<= T20, lossless gate).
// Pass2: f32-gated ballot; key build (value desc, index asc = lax.top_k) only in events.
__global__ __launch_bounds__(512, 4) void k1_knn_edge(const float* __restrict__ x,
    const float* __restrict__ w1, const float* __restrict__ g1, const float* __restrict__ b1,
    const float* __restrict__ m1, const float* __restrict__ v1, float* __restrict__ h1) {
  __shared__ float4 pts[NPT];               // 64 KB
  __shared__ float4 swa[C1], swe[C1];       // 2 KB folded edge weights
  int bb = blockIdx.x >> 7;                 // 128 blocks per batch (never straddles)
  const float* xbs = x + (size_t)bb * NPT * 3;
  for (int t = threadIdx.x; t < NPT; t += 512) {
    float a = xbs[3*t], b = xbs[3*t+1], c = xbs[3*t+2];
    pts[t] = make_float4(a, b, c, fmaf(c, c, fmaf(b, b, a*a)));   // == reference xx chain
  }
  if (threadIdx.x < C1) {
    int o = threadIdx.x;
    float inv = g1[o] / sqrtf(v1[o] + BN_EPS);
    float bbx = b1[o] - m1[o] * inv;
    const float* w = w1 + o * 6;
    swa[o] = make_float4(w[0]*inv, w[1]*inv, w[2]*inv, 0.f);
    swe[o] = make_float4((w[3]-w[0])*inv, (w[4]-w[1])*inv, (w[5]-w[2])*inv, bbx);
  }
  __syncthreads();

  int lane = threadIdx.x & 63;
  int wv = threadIdx.x >> 6;                // wave 0..7
  int q0 = blockIdx.x * 32 + wv * 4;        // first of this wave's 4 queries (global id)

  float4 q2[4];
#pragma unroll
  for (int i = 0; i < 4; ++i) {
    float4 t4 = pts[(q0 + i) & (NPT - 1)];
    q2[i] = make_float4(2.f*t4.x, 2.f*t4.y, 2.f*t4.z, -t4.w);
  }

  // ---- pass 1: lane-max per query (one b128 read serves 4 queries) ----
  float lm[4] = {-INFINITY, -INFINITY, -INFINITY, -INFINITY};
#pragma unroll 4
  for (int s = 0; s < 64; ++s) {
    float4 c = pts[s * 64 + lane];
#pragma unroll
    for (int i = 0; i < 4; ++i) lm[i] = fmaxf(lm[i], pd2_of(q2[i], c));
  }

  // ---- seeds: bitonic sort (ascending) of lane-maxes; m = elem 44 = 20th largest ----
  float m[4];
#pragma unroll
  for (int i = 0; i < 4; ++i) {
    float v = lm[i];
#pragma unroll
    for (int k = 2; k <= 64; k <<= 1) {
#pragma unroll
      for (int j2 = k >> 1; j2 > 0; j2 >>= 1) {
        float o = __shfl_xor(v, j2);
        bool keepmin = (((lane & k) == 0) == ((lane & j2) == 0));
        float mn = fminf(v, o), mx = fmaxf(v, o);
        v = keepmin ? mn : mx;
      }
    }
    m[i] = __shfl(v, 64 - KNN);              // m <= true T20
  }

  // ---- pass 2: f32-gated event-inserts into distributed top-20 key lists ----
  unsigned long long lst[4] = {0ull, 0ull, 0ull, 0ull};   // lane t: t-th largest key
  unsigned long long k19[4] = {0ull, 0ull, 0ull, 0ull};   // 20th largest (wave-uniform)
  float thr[4] = {m[0], m[1], m[2], m[3]};                // f32 value gate (grows past m)
#pragma unroll 2
  for (int s = 0; s < 64; ++s) {
    float4 c = pts[s * 64 + lane];
#pragma unroll
    for (int i = 0; i < 4; ++i) {
      float p = pd2_of(q2[i], c);
      unsigned long long mm = __ballot(p >= thr[i]);
      while (mm) {
        int src = __ffsll(mm) - 1;
        mm &= mm - 1;
        // rebuild the candidate key from the source lane (event-rate work)
        float pv = __int_as_float(__builtin_amdgcn_readlane(__float_as_int(p), src));
        int ib = __float_as_int(pv);
        unsigned uk = (unsigned)(ib ^ ((ib >> 31) | 0x80000000));  // monotone f32->u32
        unsigned long long cv = ((unsigned long long)uk << 12)
                              | (unsigned)(4095 - (s * 64 + src));
        if (cv > k19[i]) {                                // exact (value, index) order
          unsigned long long kup = __shfl_up(lst[i], 1);
          if (lane == 0) kup = ~0ull;
          lst[i] = (lst[i] > cv) ? lst[i] : ((kup > cv) ? cv : kup);
          k19[i] = rl_u64(lst[i], 19);
          if (k19[i]) {                                   // decode value part -> f32 gate
            unsigned uk19 = (unsigned)(k19[i] >> 12);
            int ib19 = (uk19 & 0x80000000u) ? (int)(uk19 ^ 0x80000000u) : (int)~uk19;
            thr[i] = __int_as_float(ib19);
          }
        }
      }
    }
  }

  // ---- fused edge-conv: lane o computes channel o; q re-read from LDS (not kept live) ----
  float4 a = swa[lane], e = swe[lane];
#pragma unroll
  for (int i = 0; i < 4; ++i) {
    float4 qq = pts[(q0 + i) & (NPT - 1)];
    float base = fmaf(e.z, qq.z, fmaf(e.y, qq.y, e.x * qq.x)) + e.w;
    float mx = -INFINITY;
#pragma unroll
    for (int k = 0; k < KNN; ++k) {
      int idx = 4095 - (int)(__builtin_amdgcn_readlane((unsigned)lst[i], k) & 0xFFFu);
      float4 nb = pts[idx];                               // wave-uniform broadcast read
      mx = fmaxf(mx, fmaf(a.z, nb.z, fmaf(a.y, nb.y, a.x * nb.x)));
    }
    h1[(size_t)(q0 + i) * C1 + lane] = fmaxf(mx + base, 0.f);  // 256B coalesced
  }
}

// ---------------- K3: conv 64->128 + BN + ReLU (out-split x4: h1 re-read 16 MB) ----------------
__global__ __launch_bounds__(256) void k3_conv2(const float* __restrict__ h1,
    const float* __restrict__ w2, const float* __restrict__ g2, const float* __restrict__ b2,
    const float* __restrict__ m2, const float* __restrict__ v2, float* __restrict__ h2) {
  __shared__ float4 sw[32 * 16];            // 8 KiB: this block's 32 outs
  __shared__ float sb[32];
  int qd = blockIdx.x >> 6, ng = blockIdx.x & 63;   // 256 blocks
  int obase = qd * 32;
  if (threadIdx.x < 32) {
    int o = obase + threadIdx.x;
    float inv = g2[o] / sqrtf(v2[o] + BN_EPS);
    sb[threadIdx.x] = b2[o] - m2[o] * inv;
  }
  for (int t = threadIdx.x; t < 32 * 16; t += 256) {
    int o = obase + (t >> 4);
    float inv = g2[o] / sqrtf(v2[o] + BN_EPS);
    float4 w = ((const float4*)w2)[o * 16 + (t & 15)];
    sw[t] = make_float4(w.x*inv, w.y*inv, w.z*inv, w.w*inv);
  }
  __syncthreads();
  int gp = ng * 256 + threadIdx.x;
  float4 r[16];
  const float4* row = (const float4*)(h1 + (size_t)gp * C1);
#pragma unroll
  for (int i = 0; i < 16; ++i) r[i] = row[i];
  float* out = h2 + (size_t)gp * C2 + obase;
#pragma unroll 1
  for (int o = 0; o < 32; o += 4) {
    float4 res;
    float* rp = &res.x;
#pragma unroll
    for (int oo = 0; oo < 4; ++oo) {
      const float4* wrow = &sw[(o+oo) * 16];
      float acc = 0.f;
#pragma unroll
      for (int i = 0; i < 16; ++i) {
        float4 w = wrow[i];
        acc = fmaf(r[i].x, w.x, acc);
        acc = fmaf(r[i].y, w.y, acc);
        acc = fmaf(r[i].z, w.z, acc);
        acc = fmaf(r[i].w, w.w, acc);
      }
      rp[oo] = fmaxf(acc + sb[o+oo], 0.f);
    }
    *(float4*)(out + o) = res;
  }
}

// ---------------- K4: conv 128->256 + BN + ReLU + 256-row max (out-split x4: 32 MB) ----------------
__global__ __launch_bounds__(256) void k4_conv3max(const float* __restrict__ h2,
    const float* __restrict__ w3, const float* __restrict__ g3, const float* __restrict__ b3,
    const float* __restrict__ m3, const float* __restrict__ v3, float* __restrict__ part) {
  __shared__ float4 sw[64 * 32];            // 32 KiB: 64 outs x 128 in
  __shared__ float sb[64], sinv[64];
  __shared__ float lw[4 * 64];
  int bid = blockIdx.x;                     // 256 = oq4 (high) x b4 x nt16
  int oq = bid >> 6, b = (bid >> 4) & 3, nt = bid & 15;
  int obase = oq * 64;
  if (threadIdx.x < 64) {
    int o = obase + threadIdx.x;
    float inv = g3[o] / sqrtf(v3[o] + BN_EPS);
    sinv[threadIdx.x] = inv;
    sb[threadIdx.x] = b3[o] - m3[o] * inv;
  }
  __syncthreads();
  for (int t = threadIdx.x; t < 64 * 32; t += 256) {
    float4 w = ((const float4*)w3)[(obase + (t >> 5)) * 32 + (t & 31)];
    float inv = sinv[t >> 5];
    sw[t] = make_float4(w.x*inv, w.y*inv, w.z*inv, w.w*inv);
  }
  __syncthreads();
  int n = nt * 256 + threadIdx.x;
  float4 r[32];
  const float4* row = (const float4*)(h2 + (size_t)(b * NPT + n) * C2);
#pragma unroll
  for (int i = 0; i < 32; ++i) r[i] = row[i];
  int lane = threadIdx.x & 63, wid = threadIdx.x >> 6;
#pragma unroll 1
  for (int ol = 0; ol < 64; ++ol) {
    const float4* wrow = &sw[ol * 32];
    float acc = 0.f;
#pragma unroll
    for (int i = 0; i < 32; ++i) {
      float4 w = wrow[i];
      acc = fmaf(r[i].x, w.x, acc);
      acc = fmaf(r[i].y, w.y, acc);
      acc = fmaf(r[i].z, w.z, acc);
      acc = fmaf(r[i].w, w.w, acc);
    }
    float v = fmaxf(acc + sb[ol], 0.f);
#pragma unroll
    for (int m = 32; m; m >>= 1) v = fmaxf(v, __shfl_xor(v, m));
    if (lane == 0) lw[wid * 64 + ol] = v;
  }
  __syncthreads();
  if (threadIdx.x < 64) {
    float m0 = fmaxf(fmaxf(lw[threadIdx.x], lw[64 + threadIdx.x]),
                     fmaxf(lw[128 + threadIdx.x], lw[192 + threadIdx.x]));
    part[bid * 64 + threadIdx.x] = m0;      // unconditional: no init/atomic needed
  }
}

// ---------------- K6: nt-reduce + FC head, one block per batch ----------------
__global__ __launch_bounds__(256) void k6_fc(const float* __restrict__ part,
    const float* __restrict__ fc1w, const float* __restrict__ fc1b,
    const float* __restrict__ fc2w, const float* __restrict__ fc2b, float* __restrict__ out) {
  __shared__ float sf[C3];
  __shared__ float pt[128][2];
  __shared__ float sh[128];
  __shared__ float p2[40][4];
  int b = blockIdx.x;
  int t = threadIdx.x;
  {                                           // feat[t] = max over nt of part[(oq*64+b*16+nt)][ol]
    int oq = t >> 6, ol = t & 63;
    const float* pp = part + (size_t)(oq * 64 + b * 16) * 64 + ol;
    float mx = pp[0];
#pragma unroll
    for (int nt = 1; nt < 16; ++nt) mx = fmaxf(mx, pp[nt * 64]);
    sf[t] = mx;
  }
  __syncthreads();
  {                                           // fc1: 128 outs x 2 half-dots
    int o = t >> 1, half = t & 1;
    const float* w = fc1w + o * C3 + half * 128;
    const float* f = sf + half * 128;
    float acc = 0.f;
#pragma unroll
    for (int c = 0; c < 128; ++c) acc = fmaf(f[c], w[c], acc);
    pt[o][half] = acc;
  }
  __syncthreads();
  if (t < 128) sh[t] = fmaxf(pt[t][0] + pt[t][1] + fc1b[t], 0.f);
  __syncthreads();
  if (t < 160) {                              // fc2: 40 outs x 4 quarter-dots
    int o = t >> 2, qtr = t & 3;
    const float* w = fc2w + o * 128 + qtr * 32;
    float acc = 0.f;
#pragma unroll
    for (int c = 0; c < 32; ++c) acc = fmaf(sh[qtr * 32 + c], w[c], acc);
    p2[o][qtr] = acc;
  }
  __syncthreads();
  if (t < 40) out[b * 40 + t] = p2[t][0] + p2[t][1] + p2[t][2] + p2[t][3] + fc2b[t];
}

extern "C" void kernel_launch(void* const* d_in, const int* in_sizes, int n_in,
                              void* d_out, int out_size, void* d_ws, size_t ws_size,
                              hipStream_t stream) {
  (void)in_sizes; (void)n_in; (void)out_size; (void)ws_size;
  const float* x   = (const float*)d_in[0];
  const float* w1  = (const float*)d_in[1];
  const float* g1  = (const float*)d_in[2];
  const float* b1  = (const float*)d_in[3];
  const float* m1  = (const float*)d_in[4];
  const float* v1  = (const float*)d_in[5];
  const float* w2  = (const float*)d_in[6];
  const float* g2  = (const float*)d_in[7];
  const float* b2  = (const float*)d_in[8];
  const float* m2  = (const float*)d_in[9];
  const float* v2  = (const float*)d_in[10];
  const float* w3  = (const float*)d_in[11];
  const float* g3  = (const float*)d_in[12];
  const float* b3  = (const float*)d_in[13];
  const float* m3  = (const float*)d_in[14];
  const float* v3  = (const float*)d_in[15];
  const float* f1w = (const float*)d_in[16];
  const float* f1b = (const float*)d_in[17];
  const float* f2w = (const float*)d_in[18];
  const float* f2b = (const float*)d_in[19];

  char* ws = (char*)d_ws;
  float* part = (float*)(ws + 0x40000);        // [256K, +64K) 256 blocks x 64 maxima
  float* h1   = (float*)(ws + 0x200000);       // [2M, 6M)
  float* h2   = (float*)(ws + 0x600000);       // [6M, 14M)

  k1_knn_edge<<<512, 512, 0, stream>>>(x, w1, g1, b1, m1, v1, h1);
  k3_conv2   <<<256, 256, 0, stream>>>(h1, w2, g2, b2, m2, v2, h2);
  k4_conv3max<<<256, 256, 0, stream>>>(h2, w3, g3, b3, m3, v3, part);
  k6_fc      <<<NB, 256, 0, stream>>>(part, f1w, f1b, f2w, f2b, (float*)d_out);
}

// Round 16
// 126.519 us; speedup vs baseline: 1.0002x; 1.0002x over previous
//
#include <hip/hip_runtime.h>
#include <math.h>

#define NB 4
#define NPT 4096
#define KNN 20
#define C1 64
#define C2 128
#define C3 256
#define BN_EPS 1e-5f

// pd = 2*dot(q,c) - |q|^2 - |c|^2 (== reference -xx - inner - cc), 4-instr form.
// q2 = {2qx, 2qy, 2qz, -|q|^2}. Same chain in both passes: selection self-consistent.
__device__ __forceinline__ float pd2_of(float4 q2, float4 c) {
#pragma clang fp contract(off)
  return fmaf(q2.x, c.x, fmaf(q2.y, c.y, fmaf(q2.z, c.z, q2.w - c.w)));
}

__device__ __forceinline__ unsigned long long rl_u64(unsigned long long v, int src) {
  unsigned lo = __builtin_amdgcn_readlane((unsigned)v, src);
  unsigned hi = __builtin_amdgcn_readlane((unsigned)(v >> 32), src);
  return ((unsigned long long)hi << 32) | lo;
}

// ---------------- K1: fused pack + exact kNN + edge-conv(6->64)+BN+ReLU+maxK ----------------
// R9 structure (loop pragmas untouched -- R10 showed full unroll => spill), pd now 4 instr.
// 512-thr blocks (8 waves), wave owns 4 queries (one ds_read_b128 feeds 4 pd).
// Pass1: lane-max + bitonic -> m = 20th-largest lane-max (<= T20, lossless gate).
// Pass2: f32-gated ballot; key build (value desc, index asc = lax.top_k) only in events.
__global__ __launch_bounds__(512, 4) void k1_knn_edge(const float* __restrict__ x,
    const float* __restrict__ w1, const float* __restrict__ g1, const float* __restrict__ b1,
    const float* __restrict__ m1, const float* __restrict__ v1, float* __restrict__ h1) {
  __shared__ float4 pts[NPT];               // 64 KB
  __shared__ float4 swa[C1], swe[C1];       // 2 KB folded edge weights
  int bb = blockIdx.x >> 7;                 // 128 blocks per batch (never straddles)
  const float* xbs = x + (size_t)bb * NPT * 3;
  for (int t = threadIdx.x; t < NPT; t += 512) {
    float a = xbs[3*t], b = xbs[3*t+1], c = xbs[3*t+2];
    pts[t] = make_float4(a, b, c, fmaf(c, c, fmaf(b, b, a*a)));   // == reference xx chain
  }
  if (threadIdx.x < C1) {
    int o = threadIdx.x;
    float inv = g1[o] / sqrtf(v1[o] + BN_EPS);
    float bbx = b1[o] - m1[o] * inv;
    const float* w = w1 + o * 6;
    swa[o] = make_float4(w[0]*inv, w[1]*inv, w[2]*inv, 0.f);
    swe[o] = make_float4((w[3]-w[0])*inv, (w[4]-w[1])*inv, (w[5]-w[2])*inv, bbx);
  }
  __syncthreads();

  int lane = threadIdx.x & 63;
  int wv = threadIdx.x >> 6;                // wave 0..7
  int q0 = blockIdx.x * 32 + wv * 4;        // first of this wave's 4 queries (global id)

  float4 q2[4];
#pragma unroll
  for (int i = 0; i < 4; ++i) {
    float4 t4 = pts[(q0 + i) & (NPT - 1)];
    q2[i] = make_float4(2.f*t4.x, 2.f*t4.y, 2.f*t4.z, -t4.w);
  }

  // ---- pass 1: lane-max per query (one b128 read serves 4 queries) ----
  float lm[4] = {-INFINITY, -INFINITY, -INFINITY, -INFINITY};
#pragma unroll 4
  for (int s = 0; s < 64; ++s) {
    float4 c = pts[s * 64 + lane];
#pragma unroll
    for (int i = 0; i < 4; ++i) lm[i] = fmaxf(lm[i], pd2_of(q2[i], c));
  }

  // ---- seeds: bitonic sort (ascending) of lane-maxes; m = elem 44 = 20th largest ----
  float m[4];
#pragma unroll
  for (int i = 0; i < 4; ++i) {
    float v = lm[i];
#pragma unroll
    for (int k = 2; k <= 64; k <<= 1) {
#pragma unroll
      for (int j2 = k >> 1; j2 > 0; j2 >>= 1) {
        float o = __shfl_xor(v, j2);
        bool keepmin = (((lane & k) == 0) == ((lane & j2) == 0));
        float mn = fminf(v, o), mx = fmaxf(v, o);
        v = keepmin ? mn : mx;
      }
    }
    m[i] = __shfl(v, 64 - KNN);              // m <= true T20
  }

  // ---- pass 2: f32-gated event-inserts into distributed top-20 key lists ----
  unsigned long long lst[4] = {0ull, 0ull, 0ull, 0ull};   // lane t: t-th largest key
  unsigned long long k19[4] = {0ull, 0ull, 0ull, 0ull};   // 20th largest (wave-uniform)
  float thr[4] = {m[0], m[1], m[2], m[3]};                // f32 value gate (grows past m)
#pragma unroll 2
  for (int s = 0; s < 64; ++s) {
    float4 c = pts[s * 64 + lane];
#pragma unroll
    for (int i = 0; i < 4; ++i) {
      float p = pd2_of(q2[i], c);
      unsigned long long mm = __ballot(p >= thr[i]);
      while (mm) {
        int src = __ffsll(mm) - 1;
        mm &= mm - 1;
        // rebuild the candidate key from the source lane (event-rate work)
        float pv = __int_as_float(__builtin_amdgcn_readlane(__float_as_int(p), src));
        int ib = __float_as_int(pv);
        unsigned uk = (unsigned)(ib ^ ((ib >> 31) | 0x80000000));  // monotone f32->u32
        unsigned long long cv = ((unsigned long long)uk << 12)
                              | (unsigned)(4095 - (s * 64 + src));
        if (cv > k19[i]) {                                // exact (value, index) order
          unsigned long long kup = __shfl_up(lst[i], 1);
          if (lane == 0) kup = ~0ull;
          lst[i] = (lst[i] > cv) ? lst[i] : ((kup > cv) ? cv : kup);
          k19[i] = rl_u64(lst[i], 19);
          if (k19[i]) {                                   // decode value part -> f32 gate
            unsigned uk19 = (unsigned)(k19[i] >> 12);
            int ib19 = (uk19 & 0x80000000u) ? (int)(uk19 ^ 0x80000000u) : (int)~uk19;
            thr[i] = __int_as_float(ib19);
          }
        }
      }
    }
  }

  // ---- fused edge-conv: lane o computes channel o; q re-read from LDS (not kept live) ----
  float4 a = swa[lane], e = swe[lane];
#pragma unroll
  for (int i = 0; i < 4; ++i) {
    float4 qq = pts[(q0 + i) & (NPT - 1)];
    float base = fmaf(e.z, qq.z, fmaf(e.y, qq.y, e.x * qq.x)) + e.w;
    float mx = -INFINITY;
#pragma unroll
    for (int k = 0; k < KNN; ++k) {
      int idx = 4095 - (int)(__builtin_amdgcn_readlane((unsigned)lst[i], k) & 0xFFFu);
      float4 nb = pts[idx];                               // wave-uniform broadcast read
      mx = fmaxf(mx, fmaf(a.z, nb.z, fmaf(a.y, nb.y, a.x * nb.x)));
    }
    h1[(size_t)(q0 + i) * C1 + lane] = fmaxf(mx + base, 0.f);  // 256B coalesced
  }
}

// ---------------- K3: conv 64->128 + BN + ReLU (out-split x4: h1 re-read 16 MB) ----------------
__global__ __launch_bounds__(256) void k3_conv2(const float* __restrict__ h1,
    const float* __restrict__ w2, const float* __restrict__ g2, const float* __restrict__ b2,
    const float* __restrict__ m2, const float* __restrict__ v2, float* __restrict__ h2) {
  __shared__ float4 sw[32 * 16];            // 8 KiB: this block's 32 outs
  __shared__ float sb[32];
  int qd = blockIdx.x >> 6, ng = blockIdx.x & 63;   // 256 blocks
  int obase = qd * 32;
  if (threadIdx.x < 32) {
    int o = obase + threadIdx.x;
    float inv = g2[o] / sqrtf(v2[o] + BN_EPS);
    sb[threadIdx.x] = b2[o] - m2[o] * inv;
  }
  for (int t = threadIdx.x; t < 32 * 16; t += 256) {
    int o = obase + (t >> 4);
    float inv = g2[o] / sqrtf(v2[o] + BN_EPS);
    float4 w = ((const float4*)w2)[o * 16 + (t & 15)];
    sw[t] = make_float4(w.x*inv, w.y*inv, w.z*inv, w.w*inv);
  }
  __syncthreads();
  int gp = ng * 256 + threadIdx.x;
  float4 r[16];
  const float4* row = (const float4*)(h1 + (size_t)gp * C1);
#pragma unroll
  for (int i = 0; i < 16; ++i) r[i] = row[i];
  float* out = h2 + (size_t)gp * C2 + obase;
#pragma unroll 1
  for (int o = 0; o < 32; o += 4) {
    float4 res;
    float* rp = &res.x;
#pragma unroll
    for (int oo = 0; oo < 4; ++oo) {
      const float4* wrow = &sw[(o+oo) * 16];
      float acc = 0.f;
#pragma unroll
      for (int i = 0; i < 16; ++i) {
        float4 w = wrow[i];
        acc = fmaf(r[i].x, w.x, acc);
        acc = fmaf(r[i].y, w.y, acc);
        acc = fmaf(r[i].z, w.z, acc);
        acc = fmaf(r[i].w, w.w, acc);
      }
      rp[oo] = fmaxf(acc + sb[o+oo], 0.f);
    }
    *(float4*)(out + o) = res;
  }
}

// ---------------- K4: conv 128->256 + BN + ReLU + 256-row max (out-split x4: 32 MB) ----------------
__global__ __launch_bounds__(256) void k4_conv3max(const float* __restrict__ h2,
    const float* __restrict__ w3, const float* __restrict__ g3, const float* __restrict__ b3,
    const float* __restrict__ m3, const float* __restrict__ v3, float* __restrict__ part) {
  __shared__ float4 sw[64 * 32];            // 32 KiB: 64 outs x 128 in
  __shared__ float sb[64], sinv[64];
  __shared__ float lw[4 * 64];
  int bid = blockIdx.x;                     // 256 = oq4 (high) x b4 x nt16
  int oq = bid >> 6, b = (bid >> 4) & 3, nt = bid & 15;
  int obase = oq * 64;
  if (threadIdx.x < 64) {
    int o = obase + threadIdx.x;
    float inv = g3[o] / sqrtf(v3[o] + BN_EPS);
    sinv[threadIdx.x] = inv;
    sb[threadIdx.x] = b3[o] - m3[o] * inv;
  }
  __syncthreads();
  for (int t = threadIdx.x; t < 64 * 32; t += 256) {
    float4 w = ((const float4*)w3)[(obase + (t >> 5)) * 32 + (t & 31)];
    float inv = sinv[t >> 5];
    sw[t] = make_float4(w.x*inv, w.y*inv, w.z*inv, w.w*inv);
  }
  __syncthreads();
  int n = nt * 256 + threadIdx.x;
  float4 r[32];
  const float4* row = (const float4*)(h2 + (size_t)(b * NPT + n) * C2);
#pragma unroll
  for (int i = 0; i < 32; ++i) r[i] = row[i];
  int lane = threadIdx.x & 63, wid = threadIdx.x >> 6;
#pragma unroll 1
  for (int ol = 0; ol < 64; ++ol) {
    const float4* wrow = &sw[ol * 32];
    float acc = 0.f;
#pragma unroll
    for (int i = 0; i < 32; ++i) {
      float4 w = wrow[i];
      acc = fmaf(r[i].x, w.x, acc);
      acc = fmaf(r[i].y, w.y, acc);
      acc = fmaf(r[i].z, w.z, acc);
      acc = fmaf(r[i].w, w.w, acc);
    }
    float v = fmaxf(acc + sb[ol], 0.f);
#pragma unroll
    for (int m = 32; m; m >>= 1) v = fmaxf(v, __shfl_xor(v, m));
    if (lane == 0) lw[wid * 64 + ol] = v;
  }
  __syncthreads();
  if (threadIdx.x < 64) {
    float m0 = fmaxf(fmaxf(lw[threadIdx.x], lw[64 + threadIdx.x]),
                     fmaxf(lw[128 + threadIdx.x], lw[192 + threadIdx.x]));
    part[bid * 64 + threadIdx.x] = m0;      // unconditional: no init/atomic needed
  }
}

// ---------------- K6: nt-reduce + FC head, one block per batch ----------------
__global__ __launch_bounds__(256) void k6_fc(const float* __restrict__ part,
    const float* __restrict__ fc1w, const float* __restrict__ fc1b,
    const float* __restrict__ fc2w, const float* __restrict__ fc2b, float* __restrict__ out) {
  __shared__ float sf[C3];
  __shared__ float pt[128][2];
  __shared__ float sh[128];
  __shared__ float p2[40][4];
  int b = blockIdx.x;
  int t = threadIdx.x;
  {                                           // feat[t] = max over nt of part[(oq*64+b*16+nt)][ol]
    int oq = t >> 6, ol = t & 63;
    const float* pp = part + (size_t)(oq * 64 + b * 16) * 64 + ol;
    float mx = pp[0];
#pragma unroll
    for (int nt = 1; nt < 16; ++nt) mx = fmaxf(mx, pp[nt * 64]);
    sf[t] = mx;
  }
  __syncthreads();
  {                                           // fc1: 128 outs x 2 half-dots
    int o = t >> 1, half = t & 1;
    const float* w = fc1w + o * C3 + half * 128;
    const float* f = sf + half * 128;
    float acc = 0.f;
#pragma unroll
    for (int c = 0; c < 128; ++c) acc = fmaf(f[c], w[c], acc);
    pt[o][half] = acc;
  }
  __syncthreads();
  if (t < 128) sh[t] = fmaxf(pt[t][0] + pt[t][1] + fc1b[t], 0.f);
  __syncthreads();
  if (t < 160) {                              // fc2: 40 outs x 4 quarter-dots
    int o = t >> 2, qtr = t & 3;
    const float* w = fc2w + o * 128 + qtr * 32;
    float acc = 0.f;
#pragma unroll
    for (int c = 0; c < 32; ++c) acc = fmaf(sh[qtr * 32 + c], w[c], acc);
    p2[o][qtr] = acc;
  }
  __syncthreads();
  if (t < 40) out[b * 40 + t] = p2[t][0] + p2[t][1] + p2[t][2] + p2[t][3] + fc2b[t];
}

extern "C" void kernel_launch(void* const* d_in, const int* in_sizes, int n_in,
                              void* d_out, int out_size, void* d_ws, size_t ws_size,
                              hipStream_t stream) {
  (void)in_sizes; (void)n_in; (void)out_size; (void)ws_size;
  const float* x   = (const float*)d_in[0];
  const float* w1  = (const float*)d_in[1];
  const float* g1  = (const float*)d_in[2];
  const float* b1  = (const float*)d_in[3];
  const float* m1  = (const float*)d_in[4];
  const float* v1  = (const float*)d_in[5];
  const float* w2  = (const float*)d_in[6];
  const float* g2  = (const float*)d_in[7];
  const float* b2  = (const float*)d_in[8];
  const float* m2  = (const float*)d_in[9];
  const float* v2  = (const float*)d_in[10];
  const float* w3  = (const float*)d_in[11];
  const float* g3  = (const float*)d_in[12];
  const float* b3  = (const float*)d_in[13];
  const float* m3  = (const float*)d_in[14];
  const float* v3  = (const float*)d_in[15];
  const float* f1w = (const float*)d_in[16];
  const float* f1b = (const float*)d_in[17];
  const float* f2w = (const float*)d_in[18];
  const float* f2b = (const float*)d_in[19];

  char* ws = (char*)d_ws;
  float* part = (float*)(ws + 0x40000);        // [256K, +64K) 256 blocks x 64 maxima
  float* h1   = (float*)(ws + 0x200000);       // [2M, 6M)
  float* h2   = (float*)(ws + 0x600000);       // [6M, 14M)

  k1_knn_edge<<<512, 512, 0, stream>>>(x, w1, g1, b1, m1, v1, h1);
  k3_conv2   <<<256, 256, 0, stream>>>(h1, w2, g2, b2, m2, v2, h2);
  k4_conv3max<<<256, 256, 0, stream>>>(h2, w3, g3, b3, m3, v3, part);
  k6_fc      <<<NB, 256, 0, stream>>>(part, f1w, f1b, f2w, f2b, (float*)d_out);
}

// Round 17
// 101.182 us; speedup vs baseline: 1.2507x; 1.2504x over previous
//
#include <hip/hip_runtime.h>
#include <math.h>

#define NB 4
#define NPT 4096
#define KNN 20
#define C1 64
#define C2 128
#define C3 256
#define BN_EPS 1e-5f

// pd = 2*dot(q,c) - |q|^2 - |c|^2 (== reference -xx - inner - cc), 4-instr form.
// q2 = {2qx, 2qy, 2qz, -|q|^2}. Same chain in both passes: selection self-consistent.
__device__ __forceinline__ float pd2_of(float4 q2, float4 c) {
#pragma clang fp contract(off)
  return fmaf(q2.x, c.x, fmaf(q2.y, c.y, fmaf(q2.z, c.z, q2.w - c.w)));
}

__device__ __forceinline__ unsigned long long rl_u64(unsigned long long v, int src) {
  unsigned lo = __builtin_amdgcn_readlane((unsigned)v, src);
  unsigned hi = __builtin_amdgcn_readlane((unsigned)(v >> 32), src);
  return ((unsigned long long)hi << 32) | lo;
}

// ---------------- K1: fused pack + exact kNN + edge-conv(6->64)+BN+ReLU+maxK ----------------
// R16-measured version (no spill, ~46us). 512-thr blocks (8 waves), wave owns 4 queries.
__global__ __launch_bounds__(512, 4) void k1_knn_edge(const float* __restrict__ x,
    const float* __restrict__ w1, const float* __restrict__ g1, const float* __restrict__ b1,
    const float* __restrict__ m1, const float* __restrict__ v1, float* __restrict__ h1) {
  __shared__ float4 pts[NPT];               // 64 KB
  __shared__ float4 swa[C1], swe[C1];       // 2 KB folded edge weights
  int bb = blockIdx.x >> 7;                 // 128 blocks per batch (never straddles)
  const float* xbs = x + (size_t)bb * NPT * 3;
  for (int t = threadIdx.x; t < NPT; t += 512) {
    float a = xbs[3*t], b = xbs[3*t+1], c = xbs[3*t+2];
    pts[t] = make_float4(a, b, c, fmaf(c, c, fmaf(b, b, a*a)));   // == reference xx chain
  }
  if (threadIdx.x < C1) {
    int o = threadIdx.x;
    float inv = g1[o] / sqrtf(v1[o] + BN_EPS);
    float bbx = b1[o] - m1[o] * inv;
    const float* w = w1 + o * 6;
    swa[o] = make_float4(w[0]*inv, w[1]*inv, w[2]*inv, 0.f);
    swe[o] = make_float4((w[3]-w[0])*inv, (w[4]-w[1])*inv, (w[5]-w[2])*inv, bbx);
  }
  __syncthreads();

  int lane = threadIdx.x & 63;
  int wv = threadIdx.x >> 6;                // wave 0..7
  int q0 = blockIdx.x * 32 + wv * 4;        // first of this wave's 4 queries (global id)

  float4 q2[4];
#pragma unroll
  for (int i = 0; i < 4; ++i) {
    float4 t4 = pts[(q0 + i) & (NPT - 1)];
    q2[i] = make_float4(2.f*t4.x, 2.f*t4.y, 2.f*t4.z, -t4.w);
  }

  // ---- pass 1: lane-max per query (one b128 read serves 4 queries) ----
  float lm[4] = {-INFINITY, -INFINITY, -INFINITY, -INFINITY};
#pragma unroll 4
  for (int s = 0; s < 64; ++s) {
    float4 c = pts[s * 64 + lane];
#pragma unroll
    for (int i = 0; i < 4; ++i) lm[i] = fmaxf(lm[i], pd2_of(q2[i], c));
  }

  // ---- seeds: bitonic sort (ascending) of lane-maxes; m = elem 44 = 20th largest ----
  float m[4];
#pragma unroll
  for (int i = 0; i < 4; ++i) {
    float v = lm[i];
#pragma unroll
    for (int k = 2; k <= 64; k <<= 1) {
#pragma unroll
      for (int j2 = k >> 1; j2 > 0; j2 >>= 1) {
        float o = __shfl_xor(v, j2);
        bool keepmin = (((lane & k) == 0) == ((lane & j2) == 0));
        float mn = fminf(v, o), mx = fmaxf(v, o);
        v = keepmin ? mn : mx;
      }
    }
    m[i] = __shfl(v, 64 - KNN);              // m <= true T20
  }

  // ---- pass 2: f32-gated event-inserts into distributed top-20 key lists ----
  unsigned long long lst[4] = {0ull, 0ull, 0ull, 0ull};   // lane t: t-th largest key
  unsigned long long k19[4] = {0ull, 0ull, 0ull, 0ull};   // 20th largest (wave-uniform)
  float thr[4] = {m[0], m[1], m[2], m[3]};                // f32 value gate (grows past m)
#pragma unroll 2
  for (int s = 0; s < 64; ++s) {
    float4 c = pts[s * 64 + lane];
#pragma unroll
    for (int i = 0; i < 4; ++i) {
      float p = pd2_of(q2[i], c);
      unsigned long long mm = __ballot(p >= thr[i]);
      while (mm) {
        int src = __ffsll(mm) - 1;
        mm &= mm - 1;
        // rebuild the candidate key from the source lane (event-rate work)
        float pv = __int_as_float(__builtin_amdgcn_readlane(__float_as_int(p), src));
        int ib = __float_as_int(pv);
        unsigned uk = (unsigned)(ib ^ ((ib >> 31) | 0x80000000));  // monotone f32->u32
        unsigned long long cv = ((unsigned long long)uk << 12)
                              | (unsigned)(4095 - (s * 64 + src));
        if (cv > k19[i]) {                                // exact (value, index) order
          unsigned long long kup = __shfl_up(lst[i], 1);
          if (lane == 0) kup = ~0ull;
          lst[i] = (lst[i] > cv) ? lst[i] : ((kup > cv) ? cv : kup);
          k19[i] = rl_u64(lst[i], 19);
          if (k19[i]) {                                   // decode value part -> f32 gate
            unsigned uk19 = (unsigned)(k19[i] >> 12);
            int ib19 = (uk19 & 0x80000000u) ? (int)(uk19 ^ 0x80000000u) : (int)~uk19;
            thr[i] = __int_as_float(ib19);
          }
        }
      }
    }
  }

  // ---- fused edge-conv: lane o computes channel o; q re-read from LDS (not kept live) ----
  float4 a = swa[lane], e = swe[lane];
#pragma unroll
  for (int i = 0; i < 4; ++i) {
    float4 qq = pts[(q0 + i) & (NPT - 1)];
    float base = fmaf(e.z, qq.z, fmaf(e.y, qq.y, e.x * qq.x)) + e.w;
    float mx = -INFINITY;
#pragma unroll
    for (int k = 0; k < KNN; ++k) {
      int idx = 4095 - (int)(__builtin_amdgcn_readlane((unsigned)lst[i], k) & 0xFFFu);
      float4 nb = pts[idx];                               // wave-uniform broadcast read
      mx = fmaxf(mx, fmaf(a.z, nb.z, fmaf(a.y, nb.y, a.x * nb.x)));
    }
    h1[(size_t)(q0 + i) * C1 + lane] = fmaxf(mx + base, 0.f);  // 256B coalesced
  }
}

// ---------------- K3: conv 64->128 + BN + ReLU (out-split x8: 2 blocks/CU, R10-measured) ----------------
__global__ __launch_bounds__(256) void k3_conv2(const float* __restrict__ h1,
    const float* __restrict__ w2, const float* __restrict__ g2, const float* __restrict__ b2,
    const float* __restrict__ m2, const float* __restrict__ v2, float* __restrict__ h2) {
  __shared__ float4 sw[16 * 16];            // 4 KiB: this block's 16 outs
  __shared__ float sb[16];
  int qd = blockIdx.x >> 6, ng = blockIdx.x & 63;   // 512 blocks, oq in HIGH bits
  int obase = qd * 16;
  if (threadIdx.x < 16) {
    int o = obase + threadIdx.x;
    float inv = g2[o] / sqrtf(v2[o] + BN_EPS);
    sb[threadIdx.x] = b2[o] - m2[o] * inv;
  }
  for (int t = threadIdx.x; t < 16 * 16; t += 256) {
    int o = obase + (t >> 4);
    float inv = g2[o] / sqrtf(v2[o] + BN_EPS);
    float4 w = ((const float4*)w2)[o * 16 + (t & 15)];
    sw[t] = make_float4(w.x*inv, w.y*inv, w.z*inv, w.w*inv);
  }
  __syncthreads();
  int gp = ng * 256 + threadIdx.x;
  float4 r[16];
  const float4* row = (const float4*)(h1 + (size_t)gp * C1);
#pragma unroll
  for (int i = 0; i < 16; ++i) r[i] = row[i];
  float* out = h2 + (size_t)gp * C2 + obase;
#pragma unroll 1
  for (int o = 0; o < 16; o += 4) {
    float4 res;
    float* rp = &res.x;
#pragma unroll
    for (int oo = 0; oo < 4; ++oo) {
      const float4* wrow = &sw[(o+oo) * 16];
      float acc = 0.f;
#pragma unroll
      for (int i = 0; i < 16; ++i) {
        float4 w = wrow[i];
        acc = fmaf(r[i].x, w.x, acc);
        acc = fmaf(r[i].y, w.y, acc);
        acc = fmaf(r[i].z, w.z, acc);
        acc = fmaf(r[i].w, w.w, acc);
      }
      rp[oo] = fmaxf(acc + sb[o+oo], 0.f);
    }
    *(float4*)(out + o) = res;
  }
}

// ---------------- K4: conv 128->256 + BN + ReLU + 256-row max -> part[bid][32] (R10-measured) ----------------
__global__ __launch_bounds__(256) void k4_conv3max(const float* __restrict__ h2,
    const float* __restrict__ w3, const float* __restrict__ g3, const float* __restrict__ b3,
    const float* __restrict__ m3, const float* __restrict__ v3, float* __restrict__ part) {
  __shared__ float4 sw[32 * 32];            // 16 KiB: 32 outs x 128 in
  __shared__ float sb[32], sinv[32];
  __shared__ float lw[4 * 32];
  int bid = blockIdx.x;                     // 512 = oq8 (high) x b4 x nt16
  int oq = bid >> 6, b = (bid >> 4) & 3, nt = bid & 15;
  int obase = oq * 32;
  if (threadIdx.x < 32) {
    int o = obase + threadIdx.x;
    float inv = g3[o] / sqrtf(v3[o] + BN_EPS);
    sinv[threadIdx.x] = inv;
    sb[threadIdx.x] = b3[o] - m3[o] * inv;
  }
  __syncthreads();
  for (int t = threadIdx.x; t < 32 * 32; t += 256) {
    float4 w = ((const float4*)w3)[(obase + (t >> 5)) * 32 + (t & 31)];
    float inv = sinv[t >> 5];
    sw[t] = make_float4(w.x*inv, w.y*inv, w.z*inv, w.w*inv);
  }
  __syncthreads();
  int n = nt * 256 + threadIdx.x;
  float4 r[32];
  const float4* row = (const float4*)(h2 + (size_t)(b * NPT + n) * C2);
#pragma unroll
  for (int i = 0; i < 32; ++i) r[i] = row[i];
  int lane = threadIdx.x & 63, wid = threadIdx.x >> 6;
#pragma unroll 1
  for (int ol = 0; ol < 32; ++ol) {
    const float4* wrow = &sw[ol * 32];
    float acc = 0.f;
#pragma unroll
    for (int i = 0; i < 32; ++i) {
      float4 w = wrow[i];
      acc = fmaf(r[i].x, w.x, acc);
      acc = fmaf(r[i].y, w.y, acc);
      acc = fmaf(r[i].z, w.z, acc);
      acc = fmaf(r[i].w, w.w, acc);
    }
    float v = fmaxf(acc + sb[ol], 0.f);
#pragma unroll
    for (int m = 32; m; m >>= 1) v = fmaxf(v, __shfl_xor(v, m));
    if (lane == 0) lw[wid * 32 + ol] = v;
  }
  __syncthreads();
  if (threadIdx.x < 32) {
    float m0 = fmaxf(fmaxf(lw[threadIdx.x], lw[32 + threadIdx.x]),
                     fmaxf(lw[64 + threadIdx.x], lw[96 + threadIdx.x]));
    part[bid * 32 + threadIdx.x] = m0;      // unconditional: no init/atomic needed
  }
}

// ---------------- K6: nt-reduce + FC head, one block per batch (R10-measured) ----------------
__global__ __launch_bounds__(256) void k6_fc(const float* __restrict__ part,
    const float* __restrict__ fc1w, const float* __restrict__ fc1b,
    const float* __restrict__ fc2w, const float* __restrict__ fc2b, float* __restrict__ out) {
  __shared__ float sf[C3];
  __shared__ float pt[128][2];
  __shared__ float sh[128];
  __shared__ float p2[40][4];
  int b = blockIdx.x;
  int t = threadIdx.x;
  {                                           // feat[o] = max over nt of part[(oq*64+b*16+nt)][ol]
    int oq = t >> 5, ol = t & 31;
    const float* pp = part + (size_t)(oq * 64 + b * 16) * 32 + ol;
    float mx = pp[0];
#pragma unroll
    for (int nt = 1; nt < 16; ++nt) mx = fmaxf(mx, pp[nt * 32]);
    sf[t] = mx;
  }
  __syncthreads();
  {                                           // fc1: 128 outs x 2 half-dots
    int o = t >> 1, half = t & 1;
    const float* w = fc1w + o * C3 + half * 128;
    const float* f = sf + half * 128;
    float acc = 0.f;
#pragma unroll
    for (int c = 0; c < 128; ++c) acc = fmaf(f[c], w[c], acc);
    pt[o][half] = acc;
  }
  __syncthreads();
  if (t < 128) sh[t] = fmaxf(pt[t][0] + pt[t][1] + fc1b[t], 0.f);
  __syncthreads();
  if (t < 160) {                              // fc2: 40 outs x 4 quarter-dots
    int o = t >> 2, qtr = t & 3;
    const float* w = fc2w + o * 128 + qtr * 32;
    float acc = 0.f;
#pragma unroll
    for (int c = 0; c < 32; ++c) acc = fmaf(sh[qtr * 32 + c], w[c], acc);
    p2[o][qtr] = acc;
  }
  __syncthreads();
  if (t < 40) out[b * 40 + t] = p2[t][0] + p2[t][1] + p2[t][2] + p2[t][3] + fc2b[t];
}

extern "C" void kernel_launch(void* const* d_in, const int* in_sizes, int n_in,
                              void* d_out, int out_size, void* d_ws, size_t ws_size,
                              hipStream_t stream) {
  (void)in_sizes; (void)n_in; (void)out_size; (void)ws_size;
  const float* x   = (const float*)d_in[0];
  const float* w1  = (const float*)d_in[1];
  const float* g1  = (const float*)d_in[2];
  const float* b1  = (const float*)d_in[3];
  const float* m1  = (const float*)d_in[4];
  const float* v1  = (const float*)d_in[5];
  const float* w2  = (const float*)d_in[6];
  const float* g2  = (const float*)d_in[7];
  const float* b2  = (const float*)d_in[8];
  const float* m2  = (const float*)d_in[9];
  const float* v2  = (const float*)d_in[10];
  const float* w3  = (const float*)d_in[11];
  const float* g3  = (const float*)d_in[12];
  const float* b3  = (const float*)d_in[13];
  const float* m3  = (const float*)d_in[14];
  const float* v3  = (const float*)d_in[15];
  const float* f1w = (const float*)d_in[16];
  const float* f1b = (const float*)d_in[17];
  const float* f2w = (const float*)d_in[18];
  const float* f2b = (const float*)d_in[19];

  char* ws = (char*)d_ws;
  float* part = (float*)(ws + 0x40000);        // [256K, +64K) 512 blocks x 32 maxima
  float* h1   = (float*)(ws + 0x200000);       // [2M, 6M)
  float* h2   = (float*)(ws + 0x600000);       // [6M, 14M)

  k1_knn_edge<<<512, 512, 0, stream>>>(x, w1, g1, b1, m1, v1, h1);
  k3_conv2   <<<512, 256, 0, stream>>>(h1, w2, g2, b2, m2, v2, h2);
  k4_conv3max<<<512, 256, 0, stream>>>(h2, w3, g3, b3, m3, v3, part);
  k6_fc      <<<NB, 256, 0, stream>>>(part, f1w, f1b, f2w, f2b, (float*)d_out);
}